// Round 8
// baseline (1165.283 us; speedup 1.0000x reference)
//
#include <hip/hip_runtime.h>
#include <hip/hip_bf16.h>

#define N_NODES 40000
#define N_EDGES 640000
#define NFEAT 128
#define NGRAPHS 64
#define ECAP 1024       // LDS edge cache per 32-row block (mean 512, +22 sigma)
#define GRID_MAIN 1250  // 8 blocks/CU x 256 CU = 2048 capacity >= 1250: co-resident

// R8: dispatch-count attack. 8 serial dispatches -> 3 (memset, k_build, k_net)
// using in-kernel grid barriers (device-scope acq-rel atomics; all blocks
// resident by capacity arithmetic). Sage inner structure = R6 (proven best).

typedef __attribute__((ext_vector_type(8))) short short8;
typedef __attribute__((ext_vector_type(4))) float float4v;
typedef __attribute__((ext_vector_type(2))) float float2v;

static __device__ __forceinline__ unsigned short f2bf(float f) {
    unsigned int x = __builtin_bit_cast(unsigned int, f);
    unsigned int r = x + 0x7fffu + ((x >> 16) & 1u);
    return (unsigned short)(r >> 16);
}

// single-use grid barrier (counter pre-zeroed by host memset each launch)
static __device__ __forceinline__ void gridbar(int* bar, int nblk) {
    __syncthreads();
    if (threadIdx.x == 0) {
        __threadfence();
        __hip_atomic_fetch_add(bar, 1, __ATOMIC_ACQ_REL, __HIP_MEMORY_SCOPE_AGENT);
        while (__hip_atomic_load(bar, __ATOMIC_RELAXED, __HIP_MEMORY_SCOPE_AGENT) < nblk)
            __builtin_amdgcn_s_sleep(8);
        __threadfence();
    }
    __syncthreads();
}

// ---------------- build: count|castx|castw|zero -> scan -> fill -------------
// 1250 blocks x 256. deg pre-zeroed by host memset. 512 edges/block.
__global__ __launch_bounds__(256, 8) void k_build(
        const int* __restrict__ src, const int* __restrict__ dst,
        const float* __restrict__ x,
        const float* __restrict__ Wl0, const float* __restrict__ Wr0,
        const float* __restrict__ Wl1, const float* __restrict__ Wr1,
        const float* __restrict__ Wl2, const float* __restrict__ Wr2,
        int* __restrict__ deg, int* __restrict__ offsets, int* __restrict__ cursor,
        unsigned short* __restrict__ esrc, unsigned short* __restrict__ h0,
        unsigned short* __restrict__ Wt, float* __restrict__ pooled,
        int* __restrict__ bar, int* __restrict__ bsum) {
    int b = blockIdx.x, tid = threadIdx.x;
    __shared__ int sexcl[32];
    __shared__ int wsum[4];

    // ---- phase 1 (parallel, independent regions) ----
    {   // edge count: e = b*512 + tid + k*256  (1250*512 = 640000 exactly)
        int e0 = b * 512 + tid;
        atomicAdd(&deg[dst[e0]], 1);
        atomicAdd(&deg[dst[e0 + 256]], 1);
    }
    {   // cast x -> h0 bf16: 640000 uint4 total, 2 per thread
        const float4* xf = (const float4*)x;
        #pragma unroll
        for (int k = 0; k < 2; ++k) {
            int i = b * 512 + tid + k * 256;
            float4 p0 = xf[2 * i], p1 = xf[2 * i + 1];
            uint4 v;
            v.x = (unsigned int)f2bf(p0.x) | ((unsigned int)f2bf(p0.y) << 16);
            v.y = (unsigned int)f2bf(p0.z) | ((unsigned int)f2bf(p0.w) << 16);
            v.z = (unsigned int)f2bf(p1.x) | ((unsigned int)f2bf(p1.y) << 16);
            v.w = (unsigned int)f2bf(p1.z) | ((unsigned int)f2bf(p1.w) << 16);
            ((uint4*)h0)[i] = v;
        }
    }
    {   // cast W -> Wt [3][128 n][256 k] n-major
        int id = b * 256 + tid;
        if (id < 3 * 128 * 256) {
            int l   = id >> 15;
            int rem = id & 32767;
            int nn  = rem >> 8;
            int k   = rem & 255;
            const float* Wl = (l == 0) ? Wl0 : (l == 1) ? Wl1 : Wl2;
            const float* Wr = (l == 0) ? Wr0 : (l == 1) ? Wr1 : Wr2;
            float v = (k < 128) ? Wl[k * 128 + nn] : Wr[(k - 128) * 128 + nn];
            Wt[id] = f2bf(v);
        }
    }
    {   // zero pooled
        int id = b * 256 + tid;
        if (id < NGRAPHS * 384) pooled[id] = 0.f;
    }
    gridbar(&bar[0], GRID_MAIN);

    // ---- phase 2: block-local prefix over this block's 32 degs ----
    if (tid < 32) {
        int d = deg[b * 32 + tid];
        int incl = d;
        #pragma unroll
        for (int s = 1; s < 32; s <<= 1) {
            int t = __shfl_up(incl, s, 64);
            if (tid >= s) incl += t;
        }
        if (tid == 31) bsum[b] = incl;
        sexcl[tid] = incl - d;
    }
    gridbar(&bar[1], GRID_MAIN);

    // ---- phase 3: redundant base = sum bsum[0..b), write offsets+cursor ----
    {
        int base = 0;
        for (int j = tid; j < b; j += 256) base += bsum[j];
        #pragma unroll
        for (int s = 1; s < 64; s <<= 1) base += __shfl_xor(base, s, 64);
        if ((tid & 63) == 0) wsum[tid >> 6] = base;
        __syncthreads();
        int tot = wsum[0] + wsum[1] + wsum[2] + wsum[3];
        if (tid < 32) {
            int o = tot + sexcl[tid];
            offsets[b * 32 + tid] = o;
            cursor[b * 32 + tid]  = o;
        }
        if (b == GRID_MAIN - 1 && tid == 0) offsets[N_NODES] = N_EDGES;
    }
    gridbar(&bar[2], GRID_MAIN);

    // ---- phase 4: fill CSR ----
    #pragma unroll
    for (int k = 0; k < 2; ++k) {
        int e = b * 512 + tid + k * 256;
        int d = dst[e];
        int p = atomicAdd(&cursor[d], 1);
        esrc[p] = (unsigned short)src[e];   // node ids < 65536
    }
}

// ---------------- one SAGE layer (R6 inner structure, device fn) ------------
static __device__ void sage_layer(
        const unsigned short* __restrict__ hin,
        const int* __restrict__ offsets,
        const unsigned short* __restrict__ esrc,
        const int* __restrict__ batch,
        const unsigned short* __restrict__ Wt,
        const float* __restrict__ bias,
        unsigned short* __restrict__ hout,        // nullable
        float* __restrict__ poolseg,
        unsigned short (&As)[32][264], unsigned short (&eidx)[ECAP]) {
    int tid = threadIdx.x;
    int row0 = blockIdx.x * 32;

    int estart = offsets[row0];
    int ecnt   = offsets[row0 + 32] - estart;
    int staged = ecnt < ECAP ? ecnt : ECAP;

    // stage self half (cols 128..255)
    for (int p = 0; p < 2; ++p) {
        int ci = tid + p * 256;
        int r = ci >> 4, c8 = ci & 15;
        uint4 v = *(const uint4*)(hin + (size_t)(row0 + r) * 128 + c8 * 8);
        *(uint4*)(&As[r][128 + c8 * 8]) = v;
    }
    for (int t = tid; t < staged; t += 256) eidx[t] = esrc[estart + t];
    __syncthreads();

    // gather-aggregate into cols 0..127 (2 nodes per 16-lane group)
    {
        int grp = tid >> 4;
        int sub = tid & 15;
        for (int nn = 0; nn < 2; ++nn) {
            int r = nn * 16 + grp;
            int node = row0 + r;
            int beg = offsets[node], end = offsets[node + 1];
            float2v a0 = {0.f, 0.f}, a1 = a0, a2 = a0, a3 = a0;
            auto acc8f = [&](uint4 u, float m) {
                float2v mv = {m, m};
                float2v t0, t1, t2, t3;
                t0.x = __builtin_bit_cast(float, u.x << 16);
                t0.y = __builtin_bit_cast(float, u.x & 0xffff0000u);
                t1.x = __builtin_bit_cast(float, u.y << 16);
                t1.y = __builtin_bit_cast(float, u.y & 0xffff0000u);
                t2.x = __builtin_bit_cast(float, u.z << 16);
                t2.y = __builtin_bit_cast(float, u.z & 0xffff0000u);
                t3.x = __builtin_bit_cast(float, u.w << 16);
                t3.y = __builtin_bit_cast(float, u.w & 0xffff0000u);
                a0 = t0 * mv + a0;
                a1 = t1 * mv + a1;
                a2 = t2 * mv + a2;
                a3 = t3 * mv + a3;
            };
            if (end - estart <= staged) {
                int lj = beg - estart, lend = end - estart;
                int jmax = lend - 1;
                for (; lj < lend; lj += 8) {
                    int rem = lend - lj;               // >= 1
                    int j1 = lj + 1 <= jmax ? lj + 1 : jmax;
                    int j2 = lj + 2 <= jmax ? lj + 2 : jmax;
                    int j3 = lj + 3 <= jmax ? lj + 3 : jmax;
                    int j4 = lj + 4 <= jmax ? lj + 4 : jmax;
                    int j5 = lj + 5 <= jmax ? lj + 5 : jmax;
                    int j6 = lj + 6 <= jmax ? lj + 6 : jmax;
                    int j7 = lj + 7 <= jmax ? lj + 7 : jmax;
                    int s0 = eidx[lj], s1 = eidx[j1], s2 = eidx[j2], s3 = eidx[j3];
                    int s4 = eidx[j4], s5 = eidx[j5], s6 = eidx[j6], s7 = eidx[j7];
                    uint4 u0 = *(const uint4*)(hin + (size_t)s0 * 128 + sub * 8);
                    uint4 u1 = *(const uint4*)(hin + (size_t)s1 * 128 + sub * 8);
                    uint4 u2 = *(const uint4*)(hin + (size_t)s2 * 128 + sub * 8);
                    uint4 u3 = *(const uint4*)(hin + (size_t)s3 * 128 + sub * 8);
                    uint4 u4 = *(const uint4*)(hin + (size_t)s4 * 128 + sub * 8);
                    uint4 u5 = *(const uint4*)(hin + (size_t)s5 * 128 + sub * 8);
                    uint4 u6 = *(const uint4*)(hin + (size_t)s6 * 128 + sub * 8);
                    uint4 u7 = *(const uint4*)(hin + (size_t)s7 * 128 + sub * 8);
                    acc8f(u0, 1.f);
                    acc8f(u1, 1 < rem ? 1.f : 0.f);
                    acc8f(u2, 2 < rem ? 1.f : 0.f);
                    acc8f(u3, 3 < rem ? 1.f : 0.f);
                    acc8f(u4, 4 < rem ? 1.f : 0.f);
                    acc8f(u5, 5 < rem ? 1.f : 0.f);
                    acc8f(u6, 6 < rem ? 1.f : 0.f);
                    acc8f(u7, 7 < rem ? 1.f : 0.f);
                }
            } else {
                int jmax = end - 1;
                for (int j = beg; j < end; j += 8) {
                    int rem = end - j;                 // >= 1
                    int j1 = j + 1 <= jmax ? j + 1 : jmax;
                    int j2 = j + 2 <= jmax ? j + 2 : jmax;
                    int j3 = j + 3 <= jmax ? j + 3 : jmax;
                    int j4 = j + 4 <= jmax ? j + 4 : jmax;
                    int j5 = j + 5 <= jmax ? j + 5 : jmax;
                    int j6 = j + 6 <= jmax ? j + 6 : jmax;
                    int j7 = j + 7 <= jmax ? j + 7 : jmax;
                    int s0 = esrc[j],  s1 = esrc[j1], s2 = esrc[j2], s3 = esrc[j3];
                    int s4 = esrc[j4], s5 = esrc[j5], s6 = esrc[j6], s7 = esrc[j7];
                    uint4 u0 = *(const uint4*)(hin + (size_t)s0 * 128 + sub * 8);
                    uint4 u1 = *(const uint4*)(hin + (size_t)s1 * 128 + sub * 8);
                    uint4 u2 = *(const uint4*)(hin + (size_t)s2 * 128 + sub * 8);
                    uint4 u3 = *(const uint4*)(hin + (size_t)s3 * 128 + sub * 8);
                    uint4 u4 = *(const uint4*)(hin + (size_t)s4 * 128 + sub * 8);
                    uint4 u5 = *(const uint4*)(hin + (size_t)s5 * 128 + sub * 8);
                    uint4 u6 = *(const uint4*)(hin + (size_t)s6 * 128 + sub * 8);
                    uint4 u7 = *(const uint4*)(hin + (size_t)s7 * 128 + sub * 8);
                    acc8f(u0, 1.f);
                    acc8f(u1, 1 < rem ? 1.f : 0.f);
                    acc8f(u2, 2 < rem ? 1.f : 0.f);
                    acc8f(u3, 3 < rem ? 1.f : 0.f);
                    acc8f(u4, 4 < rem ? 1.f : 0.f);
                    acc8f(u5, 5 < rem ? 1.f : 0.f);
                    acc8f(u6, 6 < rem ? 1.f : 0.f);
                    acc8f(u7, 7 < rem ? 1.f : 0.f);
                }
            }
            int deg = end - beg;
            float inv = 1.f / (float)(deg > 1 ? deg : 1);
            uint4 v;
            v.x = (unsigned int)f2bf(a0.x * inv) | ((unsigned int)f2bf(a0.y * inv) << 16);
            v.y = (unsigned int)f2bf(a1.x * inv) | ((unsigned int)f2bf(a1.y * inv) << 16);
            v.z = (unsigned int)f2bf(a2.x * inv) | ((unsigned int)f2bf(a2.y * inv) << 16);
            v.w = (unsigned int)f2bf(a3.x * inv) | ((unsigned int)f2bf(a3.y * inv) << 16);
            *(uint4*)(&As[r][sub * 8]) = v;
        }
    }
    __syncthreads();

    // MFMA: 32x128 tile, K=256
    int wave = tid >> 6, lane = tid & 63;
    int quad = lane >> 4, l16 = lane & 15;
    float4v acc[2][2];
    for (int rt = 0; rt < 2; ++rt)
        for (int ct = 0; ct < 2; ++ct) acc[rt][ct] = {0.f, 0.f, 0.f, 0.f};

    int ncol0 = wave * 32;
    for (int kc = 0; kc < 8; ++kc) {
        int k0 = kc * 32 + quad * 8;
        short8 a[2], b[2];
        for (int rt = 0; rt < 2; ++rt)
            a[rt] = *(const short8*)(&As[rt * 16 + l16][k0]);
        for (int ct = 0; ct < 2; ++ct)
            b[ct] = *(const short8*)(Wt + (size_t)(ncol0 + ct * 16 + l16) * 256 + k0);
        for (int rt = 0; rt < 2; ++rt)
            for (int ct = 0; ct < 2; ++ct)
                acc[rt][ct] = __builtin_amdgcn_mfma_f32_16x16x32_bf16(
                    a[rt], b[ct], acc[rt][ct], 0, 0, 0);
    }

    // ---- epilogue: bias+relu, optional hout store, fused pooling ----
    __syncthreads();                       // all As reads done; safe to alias
    float* Ps = (float*)&As[0][0];         // [32][132] f32 tile
    int* sbatch = (int*)&eidx[0];          // eidx no longer needed
    if (tid < 32) sbatch[tid] = batch[row0 + tid];

    for (int ct = 0; ct < 2; ++ct) {
        int col = ncol0 + ct * 16 + l16;
        float bv = bias[col];
        for (int rt = 0; rt < 2; ++rt) {
            int r0 = rt * 16 + quad * 4;
            for (int i = 0; i < 4; ++i) {
                float v = acc[rt][ct][i] + bv;
                v = v > 0.f ? v : 0.f;
                if (hout) hout[(size_t)(row0 + r0 + i) * 128 + col] = f2bf(v);
                Ps[(r0 + i) * 132 + col] = v;
            }
        }
    }
    __syncthreads();

    // segment-reduce 16 rows per half (batch sorted -> few runs per block)
    {
        int half = tid >> 7;               // 0: rows 0..15, 1: rows 16..31
        int c = tid & 127;
        int rbase = half * 16;
        float accp = 0.f;
        int cur = sbatch[rbase];
        for (int r = rbase; r < rbase + 16; ++r) {
            int g = sbatch[r];
            if (g != cur) {
                atomicAdd(&poolseg[cur * 384 + c], accp);
                accp = 0.f;
                cur = g;
            }
            accp += Ps[r * 132 + c];
        }
        atomicAdd(&poolseg[cur * 384 + c], accp);
    }
}

// ---------------- net: sage x3 + final, one launch --------------------------
__global__ __launch_bounds__(256, 8) void k_net(
        const unsigned short* __restrict__ h0,
        unsigned short* __restrict__ h1,
        unsigned short* __restrict__ h2,
        const int* __restrict__ offsets,
        const unsigned short* __restrict__ esrc,
        const int* __restrict__ batch,
        const unsigned short* __restrict__ Wt,
        const float* __restrict__ b1, const float* __restrict__ b2,
        const float* __restrict__ b3,
        float* __restrict__ pooled,
        const float* __restrict__ Wlin, const float* __restrict__ blin,
        float* __restrict__ out,
        int* __restrict__ bar) {
    __shared__ __align__(16) unsigned short As[32][264];
    __shared__ __align__(16) unsigned short eidx[ECAP];

    sage_layer(h0, offsets, esrc, batch, Wt,         b1, h1, pooled,       As, eidx);
    gridbar(&bar[3], GRID_MAIN);
    sage_layer(h1, offsets, esrc, batch, Wt + 32768, b2, h2, pooled + 128, As, eidx);
    gridbar(&bar[4], GRID_MAIN);
    sage_layer(h2, offsets, esrc, batch, Wt + 65536, b3, (unsigned short*)nullptr,
               pooled + 256, As, eidx);
    gridbar(&bar[5], GRID_MAIN);

    // final: blocks 0..63, split-K x2
    if (blockIdx.x < NGRAPHS) {
        int g = blockIdx.x, t = threadIdx.x;
        int col = t & 127, half = t >> 7;
        int k0 = half * 192;
        float acc = 0.f;
        for (int k = k0; k < k0 + 192; ++k)
            acc = fmaf(pooled[g * 384 + k], Wlin[k * 128 + col], acc);
        float* part = (float*)&As[0][0];
        if (half) part[col] = acc;
        __syncthreads();
        if (!half) {
            float v = acc + part[col] + blin[col];
            out[g * 128 + col] = v > 0.f ? v : 0.f;
        }
    }
}

extern "C" void kernel_launch(void* const* d_in, const int* in_sizes, int n_in,
                              void* d_out, int out_size, void* d_ws, size_t ws_size,
                              hipStream_t stream) {
    const float* x    = (const float*)d_in[0];
    const int*   ei   = (const int*)d_in[1];
    const int*   src  = ei;
    const int*   dst  = ei + N_EDGES;
    const int*   batch = (const int*)d_in[2];
    const float* W1l = (const float*)d_in[3];
    const float* b1  = (const float*)d_in[4];
    const float* W1r = (const float*)d_in[5];
    const float* W2l = (const float*)d_in[6];
    const float* b2  = (const float*)d_in[7];
    const float* W2r = (const float*)d_in[8];
    const float* W3l = (const float*)d_in[9];
    const float* b3  = (const float*)d_in[10];
    const float* W3r = (const float*)d_in[11];
    const float* Wlin = (const float*)d_in[12];
    const float* blin = (const float*)d_in[13];
    float* out = (float*)d_out;

    char* ws = (char*)d_ws;
    size_t off = 0;
    auto alloc = [&](size_t bytes) -> char* {
        char* p = ws + off;
        off = (off + bytes + 255) & ~(size_t)255;
        return p;
    };
    int* bar     = (int*)alloc(256);                      // 8 barrier slots
    int* deg     = (int*)alloc(N_NODES * sizeof(int));    // contiguous after bar
    int* offsets = (int*)alloc((N_NODES + 1) * sizeof(int));
    int* cursor  = (int*)alloc(N_NODES * sizeof(int));
    int* bsum    = (int*)alloc(GRID_MAIN * sizeof(int));
    unsigned short* esrc = (unsigned short*)alloc(N_EDGES * sizeof(unsigned short));
    unsigned short* h0   = (unsigned short*)alloc((size_t)N_NODES * 128 * 2);
    unsigned short* h1   = (unsigned short*)alloc((size_t)N_NODES * 128 * 2);
    unsigned short* h2   = (unsigned short*)alloc((size_t)N_NODES * 128 * 2);
    unsigned short* Wt   = (unsigned short*)alloc(3 * 256 * 128 * 2);
    float* pooled = (float*)alloc(NGRAPHS * 384 * sizeof(float));

    // zero barrier slots + deg in one memset (contiguous)
    hipMemsetAsync(bar, 0, 256 + N_NODES * sizeof(int), stream);

    k_build<<<GRID_MAIN, 256, 0, stream>>>(src, dst, x,
                                           W1l, W1r, W2l, W2r, W3l, W3r,
                                           deg, offsets, cursor, esrc, h0, Wt,
                                           pooled, bar, bsum);

    k_net<<<GRID_MAIN, 256, 0, stream>>>(h0, h1, h2, offsets, esrc, batch, Wt,
                                         b1, b2, b3, pooled, Wlin, blin, out, bar);
}

// Round 9
// 323.588 us; speedup vs baseline: 3.6011x; 3.6011x over previous
//
#include <hip/hip_runtime.h>
#include <hip/hip_bf16.h>

#define N_NODES 40000
#define N_EDGES 640000
#define NFEAT 128
#define NGRAPHS 64
#define ECAP 1024   // edge-id LDS cache (mean 512, +22 sigma)
#define CHUNK 64    // edges per DMA chunk (16 KB)

// R9: gather via global_load_lds DMA pipeline. R8 proved FETCH is at the
// compulsory limit (8 XCD x 10.2MB/layer) and VGPR=32 caps in-flight loads;
// DMA-to-LDS needs no dest registers -> MLP bounded by vmcnt(63/wave) not regs.
// Chunked double buffer: issue c+1 -> vmcnt(4) -> raw barrier -> accumulate c.

typedef __attribute__((ext_vector_type(8))) short short8;
typedef __attribute__((ext_vector_type(4))) float float4v;
typedef __attribute__((ext_vector_type(2))) float float2v;

static __device__ __forceinline__ unsigned short f2bf(float f) {
    unsigned int x = __builtin_bit_cast(unsigned int, f);
    unsigned int r = x + 0x7fffu + ((x >> 16) & 1u);
    return (unsigned short)(r >> 16);
}

static __device__ __forceinline__ void stage16(const unsigned short* g,
                                               unsigned short* l) {
    // lane writes LDS at (uniform base) + lane*16 bytes; global addr per-lane
    __builtin_amdgcn_global_load_lds(
        (const __attribute__((address_space(1))) void*)g,
        (__attribute__((address_space(3))) void*)l, 16, 0, 0);
}

// ---- prep: edge count (x4) | cast x (x2) | cast W | zero pooled ------------
__global__ void k_prep(const int* __restrict__ dst, int* __restrict__ deg,
                       const float* __restrict__ x, unsigned short* __restrict__ h0,
                       const float* __restrict__ Wl0, const float* __restrict__ Wr0,
                       const float* __restrict__ Wl1, const float* __restrict__ Wr1,
                       const float* __restrict__ Wl2, const float* __restrict__ Wr2,
                       unsigned short* __restrict__ Wt, float* __restrict__ pooled) {
    int b = blockIdx.x;
    if (b < 625) {
        int e0 = b * 1024 + threadIdx.x;
        #pragma unroll
        for (int k = 0; k < 4; ++k) {
            int e = e0 + k * 256;
            if (e < N_EDGES) atomicAdd(&deg[dst[e]], 1);
        }
    } else if (b < 1875) {
        const int n = N_NODES * NFEAT / 8;
        int i0 = (b - 625) * 512 + threadIdx.x;
        const float4* xf = (const float4*)x;
        #pragma unroll
        for (int k = 0; k < 2; ++k) {
            int i = i0 + k * 256;
            if (i < n) {
                float4 p0 = xf[2 * i], p1 = xf[2 * i + 1];
                uint4 v;
                v.x = (unsigned int)f2bf(p0.x) | ((unsigned int)f2bf(p0.y) << 16);
                v.y = (unsigned int)f2bf(p0.z) | ((unsigned int)f2bf(p0.w) << 16);
                v.z = (unsigned int)f2bf(p1.x) | ((unsigned int)f2bf(p1.y) << 16);
                v.w = (unsigned int)f2bf(p1.z) | ((unsigned int)f2bf(p1.w) << 16);
                ((uint4*)h0)[i] = v;
            }
        }
    } else if (b < 2259) {
        int id = (b - 1875) * 256 + threadIdx.x;
        if (id >= 3 * 128 * 256) return;
        int l   = id >> 15;
        int rem = id & 32767;
        int nn  = rem >> 8;
        int k   = rem & 255;
        const float* Wl = (l == 0) ? Wl0 : (l == 1) ? Wl1 : Wl2;
        const float* Wr = (l == 0) ? Wr0 : (l == 1) ? Wr1 : Wr2;
        float v = (k < 128) ? Wl[k * 128 + nn] : Wr[(k - 128) * 128 + nn];
        Wt[id] = f2bf(v);
    } else {
        int j = (b - 2259) * 256 + threadIdx.x;
        if (j < NGRAPHS * 384) pooled[j] = 0.f;
    }
}

// ---------------- single-kernel scan (40 blocks, redundant prefix) ----------
__global__ __launch_bounds__(1024) void k_scan(const int* __restrict__ deg,
                                               int* __restrict__ offsets,
                                               int* __restrict__ cursor) {
    __shared__ int ws[16];
    __shared__ int s_boff;
    int tid = threadIdx.x;
    int b = blockIdx.x;
    int lane = tid & 63, wave = tid >> 6;

    int lim = b << 10;
    int s = 0;
    for (int i = tid; i < lim; i += 1024) s += deg[i];
    for (int d = 1; d < 64; d <<= 1) s += __shfl_xor(s, d, 64);
    if (lane == 0) ws[wave] = s;
    __syncthreads();
    if (tid == 0) {
        int t = 0;
        for (int w = 0; w < 16; ++w) t += ws[w];
        s_boff = t;
    }
    __syncthreads();
    int boff = s_boff;

    int i = (b << 10) + tid;
    int v = (i < N_NODES) ? deg[i] : 0;
    int incl = v;
    for (int d = 1; d < 64; d <<= 1) {
        int t = __shfl_up(incl, d, 64);
        if (lane >= d) incl += t;
    }
    __syncthreads();
    if (lane == 63) ws[wave] = incl;
    __syncthreads();
    if (wave == 0 && lane < 16) {
        int w = ws[lane];
        for (int d = 1; d < 16; d <<= 1) {
            int t = __shfl_up(w, d, 64);
            if (lane >= d) w += t;
        }
        ws[lane] = w;
    }
    __syncthreads();
    int waveOff = (wave == 0) ? 0 : ws[wave - 1];
    if (i < N_NODES) {
        int o = boff + waveOff + incl - v;
        offsets[i] = o;
        cursor[i]  = o;
    }
    if (b == 39 && tid == 0) offsets[N_NODES] = N_EDGES;
}

__global__ void k_fill(const int* __restrict__ src, const int* __restrict__ dst,
                       int* __restrict__ cursor, unsigned short* __restrict__ esrc) {
    int e0 = blockIdx.x * 512 + threadIdx.x;
    #pragma unroll
    for (int k = 0; k < 2; ++k) {
        int e = e0 + k * 256;
        if (e < N_EDGES) {
            int d = dst[e];
            int p = atomicAdd(&cursor[d], 1);
            esrc[p] = (unsigned short)src[e];   // node ids < 65536
        }
    }
}

// ---------------- fused SAGE layer + pooled epilogue ------------------------
// 32-row blocks, grid 1250, 3 blocks/CU (LDS 51.7KB). Gather: DMA-staged
// 64-edge chunks, double-buffered, counted vmcnt + raw barriers.
__global__ __launch_bounds__(256, 4) void k_sage(
        const unsigned short* __restrict__ hin,   // [N][128] row-major
        const int* __restrict__ offsets,
        const unsigned short* __restrict__ esrc,
        const int* __restrict__ batch,
        const unsigned short* __restrict__ Wt,    // [128][256] n-major
        const float* __restrict__ bias,
        unsigned short* __restrict__ hout,        // nullable
        float* __restrict__ poolseg) {            // pooled + layer*128
    __shared__ __align__(16) unsigned short As[32][264];      // 16,896 B
    __shared__ __align__(16) unsigned short Ebuf[2][CHUNK * 128]; // 32,768 B
    __shared__ __align__(16) unsigned short eidx[ECAP];       // 2,048 B
    int tid = threadIdx.x;
    int row0 = blockIdx.x * 32;

    int estart = offsets[row0];
    int ecnt   = offsets[row0 + 32] - estart;
    int SC = ecnt < ECAP ? ecnt : ECAP;

    // stage self half (cols 128..255)
    for (int p = 0; p < 2; ++p) {
        int ci = tid + p * 256;
        int r = ci >> 4, c8 = ci & 15;
        uint4 v = *(const uint4*)(hin + (size_t)(row0 + r) * 128 + c8 * 8);
        *(uint4*)(&As[r][128 + c8 * 8]) = v;
    }
    for (int t = tid; t < SC; t += 256) eidx[t] = esrc[estart + t];
    __syncthreads();

    int lane = tid & 63, wave = tid >> 6;
    int grp = tid >> 4, sub = tid & 15;

    // per-node block-local ranges + accumulators (static indices via unroll)
    int beg0, end0, beg1, end1;
    {
        int n0 = row0 + grp,      n1 = row0 + 16 + grp;
        beg0 = offsets[n0] - estart;  end0 = offsets[n0 + 1] - estart;
        beg1 = offsets[n1] - estart;  end1 = offsets[n1 + 1] - estart;
    }
    float2v A0[4], A1[4];
    #pragma unroll
    for (int i = 0; i < 4; ++i) { A0[i] = {0.f, 0.f}; A1[i] = {0.f, 0.f}; }

    auto addu = [&](uint4 u, float2v* A) {
        float2v t0, t1, t2, t3;
        t0.x = __builtin_bit_cast(float, u.x << 16);
        t0.y = __builtin_bit_cast(float, u.x & 0xffff0000u);
        t1.x = __builtin_bit_cast(float, u.y << 16);
        t1.y = __builtin_bit_cast(float, u.y & 0xffff0000u);
        t2.x = __builtin_bit_cast(float, u.z << 16);
        t2.y = __builtin_bit_cast(float, u.z & 0xffff0000u);
        t3.x = __builtin_bit_cast(float, u.w << 16);
        t3.y = __builtin_bit_cast(float, u.w & 0xffff0000u);
        A[0] += t0; A[1] += t1; A[2] += t2; A[3] += t3;
    };

    int nc = (SC + CHUNK - 1) >> 6;   // chunks of 64 edges
    if (nc > 0) {
        auto stage_chunk = [&](int c, int par) {
            int c0 = c << 6;
            #pragma unroll
            for (int i = 0; i < 4; ++i) {
                int slot = wave * 4 + i;              // 0..15
                int el = c0 + slot * 4 + (lane >> 4); // edge (may exceed SC-1)
                el = el < SC - 1 ? el : SC - 1;       // clamp: dup row, unused slot
                int s = eidx[el];
                const unsigned short* g = hin + (size_t)s * 128 + (lane & 15) * 8;
                stage16(g, &Ebuf[par][slot * 512]);   // +lane*16B by HW
            }
        };
        auto accum_chunk = [&](int c, int par) {
            int c0 = c << 6, c1 = c0 + CHUNK;
            int lim = c1 < SC ? c1 : SC;
            {
                int lo = beg0 > c0 ? beg0 : c0;
                int hi = end0 < lim ? end0 : lim;
                for (int e = lo; e < hi; ++e)
                    addu(*(const uint4*)&Ebuf[par][(e - c0) * 128 + sub * 8], A0);
            }
            {
                int lo = beg1 > c0 ? beg1 : c0;
                int hi = end1 < lim ? end1 : lim;
                for (int e = lo; e < hi; ++e)
                    addu(*(const uint4*)&Ebuf[par][(e - c0) * 128 + sub * 8], A1);
            }
        };

        stage_chunk(0, 0);
        for (int c = 0; c < nc; ++c) {
            int par = c & 1;
            if (c + 1 < nc) {
                stage_chunk(c + 1, par ^ 1);
                asm volatile("s_waitcnt vmcnt(4)" ::: "memory");
            } else {
                asm volatile("s_waitcnt vmcnt(0)" ::: "memory");
            }
            __builtin_amdgcn_sched_barrier(0);
            __builtin_amdgcn_s_barrier();
            __builtin_amdgcn_sched_barrier(0);
            accum_chunk(c, par);
            __builtin_amdgcn_sched_barrier(0);
            __builtin_amdgcn_s_barrier();
        }
    }
    // rare fallback: edges beyond ECAP (block ecnt > 1024, +22 sigma)
    if (ecnt > SC) {
        for (int e = (beg0 > SC ? beg0 : SC); e < end0; ++e) {
            int s = esrc[estart + e];
            addu(*(const uint4*)(hin + (size_t)s * 128 + sub * 8), A0);
        }
        for (int e = (beg1 > SC ? beg1 : SC); e < end1; ++e) {
            int s = esrc[estart + e];
            addu(*(const uint4*)(hin + (size_t)s * 128 + sub * 8), A1);
        }
    }

    // divide + pack both nodes into As cols 0..127
    {
        int d0 = end0 - beg0;
        float inv0 = 1.f / (float)(d0 > 1 ? d0 : 1);
        uint4 v;
        v.x = (unsigned int)f2bf(A0[0].x * inv0) | ((unsigned int)f2bf(A0[0].y * inv0) << 16);
        v.y = (unsigned int)f2bf(A0[1].x * inv0) | ((unsigned int)f2bf(A0[1].y * inv0) << 16);
        v.z = (unsigned int)f2bf(A0[2].x * inv0) | ((unsigned int)f2bf(A0[2].y * inv0) << 16);
        v.w = (unsigned int)f2bf(A0[3].x * inv0) | ((unsigned int)f2bf(A0[3].y * inv0) << 16);
        *(uint4*)(&As[grp][sub * 8]) = v;
        int d1 = end1 - beg1;
        float inv1 = 1.f / (float)(d1 > 1 ? d1 : 1);
        uint4 w;
        w.x = (unsigned int)f2bf(A1[0].x * inv1) | ((unsigned int)f2bf(A1[0].y * inv1) << 16);
        w.y = (unsigned int)f2bf(A1[1].x * inv1) | ((unsigned int)f2bf(A1[1].y * inv1) << 16);
        w.z = (unsigned int)f2bf(A1[2].x * inv1) | ((unsigned int)f2bf(A1[2].y * inv1) << 16);
        w.w = (unsigned int)f2bf(A1[3].x * inv1) | ((unsigned int)f2bf(A1[3].y * inv1) << 16);
        *(uint4*)(&As[16 + grp][sub * 8]) = w;
    }
    __syncthreads();

    // MFMA: 32x128 tile, K=256
    int quad = lane >> 4, l16 = lane & 15;
    float4v acc[2][2];
    for (int rt = 0; rt < 2; ++rt)
        for (int ct = 0; ct < 2; ++ct) acc[rt][ct] = {0.f, 0.f, 0.f, 0.f};

    int ncol0 = wave * 32;
    for (int kc = 0; kc < 8; ++kc) {
        int k0 = kc * 32 + quad * 8;
        short8 a[2], b[2];
        for (int rt = 0; rt < 2; ++rt)
            a[rt] = *(const short8*)(&As[rt * 16 + l16][k0]);
        for (int ct = 0; ct < 2; ++ct)
            b[ct] = *(const short8*)(Wt + (size_t)(ncol0 + ct * 16 + l16) * 256 + k0);
        for (int rt = 0; rt < 2; ++rt)
            for (int ct = 0; ct < 2; ++ct)
                acc[rt][ct] = __builtin_amdgcn_mfma_f32_16x16x32_bf16(
                    a[rt], b[ct], acc[rt][ct], 0, 0, 0);
    }

    // ---- epilogue: bias+relu, optional hout store, fused pooling ----
    __syncthreads();                       // all As reads done; safe to alias
    float* Ps = (float*)&As[0][0];         // [32][132] f32 tile (16,896 B fits)
    int* sbatch = (int*)&eidx[0];          // eidx no longer needed
    if (tid < 32) sbatch[tid] = batch[row0 + tid];

    for (int ct = 0; ct < 2; ++ct) {
        int col = ncol0 + ct * 16 + l16;
        float bv = bias[col];
        for (int rt = 0; rt < 2; ++rt) {
            int r0 = rt * 16 + quad * 4;
            for (int i = 0; i < 4; ++i) {
                float v = acc[rt][ct][i] + bv;
                v = v > 0.f ? v : 0.f;
                if (hout) hout[(size_t)(row0 + r0 + i) * 128 + col] = f2bf(v);
                Ps[(r0 + i) * 132 + col] = v;
            }
        }
    }
    __syncthreads();

    // segment-reduce 16 rows per half (batch sorted -> few runs per block)
    {
        int half = tid >> 7;               // 0: rows 0..15, 1: rows 16..31
        int c = tid & 127;
        int rbase = half * 16;
        float accp = 0.f;
        int cur = sbatch[rbase];
        for (int r = rbase; r < rbase + 16; ++r) {
            int g = sbatch[r];
            if (g != cur) {
                atomicAdd(&poolseg[cur * 384 + c], accp);
                accp = 0.f;
                cur = g;
            }
            accp += Ps[r * 132 + c];
        }
        atomicAdd(&poolseg[cur * 384 + c], accp);
    }
}

// ---------------- final (split-K x2) ----------------------------------------
__global__ void k_final(const float* __restrict__ pooled,
                        const float* __restrict__ Wlin,
                        const float* __restrict__ blin,
                        float* __restrict__ out) {
    __shared__ float part[128];
    int g = blockIdx.x;
    int t = threadIdx.x;
    int col = t & 127, half = t >> 7;
    int k0 = half * 192;
    float acc = 0.f;
    for (int k = k0; k < k0 + 192; ++k)
        acc = fmaf(pooled[g * 384 + k], Wlin[k * 128 + col], acc);
    if (half) part[col] = acc;
    __syncthreads();
    if (!half) {
        float v = acc + part[col] + blin[col];
        out[g * 128 + col] = v > 0.f ? v : 0.f;
    }
}

extern "C" void kernel_launch(void* const* d_in, const int* in_sizes, int n_in,
                              void* d_out, int out_size, void* d_ws, size_t ws_size,
                              hipStream_t stream) {
    const float* x    = (const float*)d_in[0];
    const int*   ei   = (const int*)d_in[1];
    const int*   src  = ei;
    const int*   dst  = ei + N_EDGES;
    const int*   batch = (const int*)d_in[2];
    const float* W1l = (const float*)d_in[3];
    const float* b1  = (const float*)d_in[4];
    const float* W1r = (const float*)d_in[5];
    const float* W2l = (const float*)d_in[6];
    const float* b2  = (const float*)d_in[7];
    const float* W2r = (const float*)d_in[8];
    const float* W3l = (const float*)d_in[9];
    const float* b3  = (const float*)d_in[10];
    const float* W3r = (const float*)d_in[11];
    const float* Wlin = (const float*)d_in[12];
    const float* blin = (const float*)d_in[13];
    float* out = (float*)d_out;

    char* ws = (char*)d_ws;
    size_t off = 0;
    auto alloc = [&](size_t bytes) -> char* {
        char* p = ws + off;
        off = (off + bytes + 255) & ~(size_t)255;
        return p;
    };
    int* offsets = (int*)alloc((N_NODES + 1) * sizeof(int));
    int* cursor  = (int*)alloc(N_NODES * sizeof(int));
    int* deg     = (int*)alloc(N_NODES * sizeof(int));
    unsigned short* esrc = (unsigned short*)alloc(N_EDGES * sizeof(unsigned short));
    unsigned short* h0   = (unsigned short*)alloc((size_t)N_NODES * 128 * 2);
    unsigned short* h1   = (unsigned short*)alloc((size_t)N_NODES * 128 * 2);
    unsigned short* h2   = (unsigned short*)alloc((size_t)N_NODES * 128 * 2);
    unsigned short* Wt   = (unsigned short*)alloc(3 * 256 * 128 * 2);
    float* pooled = (float*)alloc(NGRAPHS * 384 * sizeof(float));

    hipMemsetAsync(deg, 0, N_NODES * sizeof(int), stream);

    k_prep<<<2355, 256, 0, stream>>>(dst, deg, x, h0,
                                     W1l, W1r, W2l, W2r, W3l, W3r, Wt, pooled);
    k_scan<<<40, 1024, 0, stream>>>(deg, offsets, cursor);
    k_fill<<<1250, 256, 0, stream>>>(src, dst, cursor, esrc);

    k_sage<<<1250, 256, 0, stream>>>(h0, offsets, esrc, batch, Wt,
                                     b1, h1, pooled);
    k_sage<<<1250, 256, 0, stream>>>(h1, offsets, esrc, batch, Wt + 32768,
                                     b2, h2, pooled + 128);
    k_sage<<<1250, 256, 0, stream>>>(h2, offsets, esrc, batch, Wt + 2 * 32768,
                                     b3, (unsigned short*)nullptr, pooled + 256);

    k_final<<<NGRAPHS, 256, 0, stream>>>(pooled, Wlin, blin, out);
}